// Round 2
// baseline (1964.727 us; speedup 1.0000x reference)
//
#include <hip/hip_runtime.h>
#include <math.h>

#define N_NODES 10000
#define N_EDGES 80000
#define ET (N_EDGES + N_NODES)   // 90000 edges incl. self-loops
#define IN_FEAT 200
#define HID 400
#define NH1 8
#define F1 (NH1 * HID)           // 3200
#define OUT_FEAT 200
#define NEG_SLOPE 0.2f
#define NT 8                     // nodes per mega-block

// ---------- helpers ----------

__device__ inline void edge_sd(const int* __restrict__ ei, int e, int& s, int& d) {
    if (e < N_EDGES) { s = ei[e]; d = ei[N_EDGES + e]; }
    else { s = e - N_EDGES; d = s; }
}

// float atomic max via int/uint ordering trick (init -inf)
__device__ inline void atomicMaxF(float* addr, float val) {
    if (val >= 0.f) atomicMax((int*)addr, __float_as_int(val));
    else            atomicMin((unsigned int*)addr, (unsigned int)__float_as_uint(val));
}

__global__ void fill_f(float* __restrict__ p, float v, int n) {
    int i = blockIdx.x * blockDim.x + threadIdx.x;
    if (i < n) p[i] = v;
}

// ---------- p-vectors: p_src1[h,k] = sum_c W1[k, h*400+c] * a_src1[h,c] ----------
__global__ __launch_bounds__(256) void pvec_k(const float* __restrict__ W1,
                                              const float* __restrict__ a_src,
                                              const float* __restrict__ a_dst,
                                              float* __restrict__ p_src,
                                              float* __restrict__ p_dst) {
    int idx = blockIdx.x * blockDim.x + threadIdx.x;  // [0, 2*8*200)
    if (idx >= 2 * NH1 * IN_FEAT) return;
    int which = idx / (NH1 * IN_FEAT);
    int r = idx - which * (NH1 * IN_FEAT);
    int h = r / IN_FEAT, k = r - h * IN_FEAT;
    const float* av = (which == 0 ? a_src : a_dst) + h * HID;
    const float* wrow = W1 + (size_t)k * F1 + h * HID;
    float acc = 0.f;
    for (int c = 0; c < HID; ++c) acc += wrow[c] * av[c];
    (which == 0 ? p_src : p_dst)[h * IN_FEAT + k] = acc;
}

// ---------- attention logits layer 1 via p-vectors: als/ald [N,8] ----------
__global__ __launch_bounds__(512) void att1x(const float* __restrict__ X,
                                             const float* __restrict__ p_src,
                                             const float* __restrict__ p_dst,
                                             float* __restrict__ als,
                                             float* __restrict__ ald) {
    const int n    = blockIdx.x;
    const int head = threadIdx.x >> 6;
    const int lane = threadIdx.x & 63;
    const float* xp = X + (size_t)n * IN_FEAT;
    const float* ps = p_src + head * IN_FEAT;
    const float* pd = p_dst + head * IN_FEAT;
    float ss = 0.f, sd = 0.f;
    for (int k = lane; k < IN_FEAT; k += 64) {
        float v = xp[k];
        ss += v * ps[k];
        sd += v * pd[k];
    }
    for (int off = 32; off; off >>= 1) {
        ss += __shfl_down(ss, off);
        sd += __shfl_down(sd, off);
    }
    if (lane == 0) { als[n * NH1 + head] = ss; ald[n * NH1 + head] = sd; }
}

// ---------- attention logits layer 2 (1 head) from h2 ----------
__global__ __launch_bounds__(64) void att2k(const float* __restrict__ Hh,
                                            const float* __restrict__ a_src,
                                            const float* __restrict__ a_dst,
                                            float* __restrict__ als,
                                            float* __restrict__ ald) {
    const int n    = blockIdx.x;
    const int lane = threadIdx.x;
    const float* hp = Hh + (size_t)n * OUT_FEAT;
    float ss = 0.f, sd = 0.f;
    for (int c = lane; c < OUT_FEAT; c += 64) {
        float v = hp[c];
        ss += v * a_src[c];
        sd += v * a_dst[c];
    }
    for (int off = 32; off; off >>= 1) {
        ss += __shfl_down(ss, off);
        sd += __shfl_down(sd, off);
    }
    if (lane == 0) { als[n] = ss; ald[n] = sd; }
}

// ---------- CSR build ----------
__global__ __launch_bounds__(256) void count_k(const int* __restrict__ ei, int* __restrict__ counts) {
    int e = blockIdx.x * blockDim.x + threadIdx.x;
    if (e >= ET) return;
    int s, d; edge_sd(ei, e, s, d);
    atomicAdd(&counts[d], 1);
}

__global__ __launch_bounds__(1024) void scan_k(const int* __restrict__ counts, int* __restrict__ offs) {
    __shared__ int part[1024];
    const int tid = threadIdx.x;
    const int base = tid * 10;  // 10240 >= 10000
    int loc[10];
    int s = 0;
    for (int i = 0; i < 10; ++i) {
        int idx = base + i;
        int c = (idx < N_NODES) ? counts[idx] : 0;
        loc[i] = s; s += c;
    }
    part[tid] = s;
    __syncthreads();
    for (int off = 1; off < 1024; off <<= 1) {
        int v = (tid >= off) ? part[tid - off] : 0;
        __syncthreads();
        part[tid] += v;
        __syncthreads();
    }
    int pre = (tid > 0) ? part[tid - 1] : 0;
    for (int i = 0; i < 10; ++i) {
        int idx = base + i;
        if (idx < N_NODES) offs[idx] = pre + loc[i];
    }
    if (tid == 1023) offs[N_NODES] = part[1023];
}

__global__ __launch_bounds__(256) void scatter_k(const int* __restrict__ ei,
                                                 const int* __restrict__ offs,
                                                 int* __restrict__ cursor,
                                                 int* __restrict__ esrc) {
    int e = blockIdx.x * blockDim.x + threadIdx.x;
    if (e >= ET) return;
    int s, d; edge_sd(ei, e, s, d);
    int pos = atomicAdd(&cursor[d], 1);
    esrc[offs[d] + pos] = s;
}

// ---------- edge softmax stats (no per-edge storage) ----------
template <int H>
__global__ __launch_bounds__(256) void edge_max_k(const int* __restrict__ ei,
                                                  const float* __restrict__ als,
                                                  const float* __restrict__ ald,
                                                  float* __restrict__ emax) {
    int idx = blockIdx.x * blockDim.x + threadIdx.x;
    if (idx >= ET * H) return;
    int e = idx / H, h = idx - e * H;
    int s, d; edge_sd(ei, e, s, d);
    float v = als[s * H + h] + ald[d * H + h];
    v = v > 0.f ? v : NEG_SLOPE * v;
    atomicMaxF(&emax[d * H + h], v);
}

template <int H>
__global__ __launch_bounds__(256) void edge_den_k(const int* __restrict__ ei,
                                                  const float* __restrict__ als,
                                                  const float* __restrict__ ald,
                                                  const float* __restrict__ emax,
                                                  float* __restrict__ den) {
    int idx = blockIdx.x * blockDim.x + threadIdx.x;
    if (idx >= ET * H) return;
    int e = idx / H, h = idx - e * H;
    int s, d; edge_sd(ei, e, s, d);
    float v = als[s * H + h] + ald[d * H + h];
    v = v > 0.f ? v : NEG_SLOPE * v;
    unsafeAtomicAdd(&den[d * H + h], __expf(v - emax[d * H + h]));
}

// ---------- mega kernel: CSR-aggregate X -> per-head GEMM1+ELU -> GEMM2 -> h2 ----------
// 512 threads (8 waves); wave w aggregates node n0+w. LDS: 51200 + 12800 = 64000 B.
__global__ __launch_bounds__(512) void mega1(const float* __restrict__ X,
                                             const float* __restrict__ W1,
                                             const float* __restrict__ b1,
                                             const float* __restrict__ als1,
                                             const float* __restrict__ ald1,
                                             const float* __restrict__ emax1,
                                             const float* __restrict__ den1,
                                             const int* __restrict__ offs,
                                             const int* __restrict__ esrc,
                                             const float* __restrict__ W2,
                                             float* __restrict__ h2out) {
    __shared__ float xagg[NT][NH1 * IN_FEAT];  // [8][1600] fp32 = 51.2 KB
    __shared__ float xh[NT][HID];              // [8][400]  fp32 = 12.8 KB
    const int n0   = blockIdx.x * NT;
    const int wave = threadIdx.x >> 6;
    const int lane = threadIdx.x & 63;

    // ---- Stage A: Xagg[n,h,:] = sum_{e into n} alpha[e,h] * X[src_e,:]
    {
        const int n = n0 + wave;
        for (int j = lane; j < NH1 * IN_FEAT; j += 64) xagg[wave][j] = 0.f;
        float aldv = 0.f, em = 0.f, dn = 1.f;
        if (lane < NH1) {
            aldv = ald1[n * NH1 + lane];
            em   = emax1[n * NH1 + lane];
            dn   = den1[n * NH1 + lane];
        }
        const int beg = offs[n], end = offs[n + 1];
        for (int t = beg; t < end; ++t) {
            const int s = esrc[t];
            float aval = 0.f;
            if (lane < NH1) {
                float v = als1[s * NH1 + lane] + aldv;
                v = v > 0.f ? v : NEG_SLOPE * v;
                aval = __expf(v - em) / dn;
            }
            const float* xp = X + (size_t)s * IN_FEAT;
            float x0 = xp[lane];
            float x1 = xp[64 + lane];
            float x2 = xp[128 + lane];
            float x3 = (lane < 8) ? xp[192 + lane] : 0.f;
#pragma unroll
            for (int h = 0; h < NH1; ++h) {
                float a = __shfl(aval, h);
                xagg[wave][h * IN_FEAT + lane]       += a * x0;
                xagg[wave][h * IN_FEAT + 64 + lane]  += a * x1;
                xagg[wave][h * IN_FEAT + 128 + lane] += a * x2;
                if (lane < 8) xagg[wave][h * IN_FEAT + 192 + lane] += a * x3;
            }
        }
    }
    __syncthreads();

    // ---- Stage B: per head h: xh = elu(xagg_h @ W1_h + b1_h); h2 += xh @ W2_h
    float h2r[4] = {0.f, 0.f, 0.f, 0.f};
    for (int h = 0; h < NH1; ++h) {
        for (int o = threadIdx.x; o < NT * HID; o += 512) {
            int nn = o / HID, c = o - nn * HID;
            float acc = b1[h * HID + c];
            const float* wcol = W1 + (size_t)h * HID + c;  // stride F1 over k
            const float* xrow = &xagg[nn][h * IN_FEAT];
            for (int k = 0; k < IN_FEAT; ++k)
                acc += xrow[k] * wcol[(size_t)k * F1];
            xh[nn][c] = acc > 0.f ? acc : (__expf(acc) - 1.f);
        }
        __syncthreads();
#pragma unroll
        for (int r = 0; r < 4; ++r) {
            int o = threadIdx.x + r * 512;
            if (o < NT * OUT_FEAT) {
                int nn = o / OUT_FEAT, m = o - nn * OUT_FEAT;
                const float* w2c = W2 + (size_t)h * HID * OUT_FEAT + m;  // stride OUT_FEAT over c
                float acc = 0.f;
                for (int c = 0; c < HID; ++c)
                    acc += xh[nn][c] * w2c[(size_t)c * OUT_FEAT];
                h2r[r] += acc;
            }
        }
        __syncthreads();
    }
#pragma unroll
    for (int r = 0; r < 4; ++r) {
        int o = threadIdx.x + r * 512;
        if (o < NT * OUT_FEAT) {
            int nn = o / OUT_FEAT, m = o - nn * OUT_FEAT;
            h2out[(size_t)(n0 + nn) * OUT_FEAT + m] = h2r[r];
        }
    }
}

// ---------- layer-2 aggregation: CSR gather of h2, + b2, write out ----------
__global__ __launch_bounds__(256) void agg2_csr(const float* __restrict__ h2,
                                                const float* __restrict__ als2,
                                                const float* __restrict__ ald2,
                                                const float* __restrict__ emax2,
                                                const float* __restrict__ den2,
                                                const int* __restrict__ offs,
                                                const int* __restrict__ esrc,
                                                const float* __restrict__ b2,
                                                float* __restrict__ out) {
    const int n = blockIdx.x;
    const int k = threadIdx.x;
    if (k >= OUT_FEAT) return;
    const float aldn = ald2[n], em = emax2[n], dn = den2[n];
    const int beg = offs[n], end = offs[n + 1];
    float acc = 0.f;
    for (int t = beg; t < end; ++t) {
        int s = esrc[t];
        float v = als2[s] + aldn;
        v = v > 0.f ? v : NEG_SLOPE * v;
        float a = __expf(v - em) / dn;
        acc += a * h2[(size_t)s * OUT_FEAT + k];
    }
    out[(size_t)n * OUT_FEAT + k] = acc + b2[k];
}

// ---------- launch ----------
extern "C" void kernel_launch(void* const* d_in, const int* in_sizes, int n_in,
                              void* d_out, int out_size, void* d_ws, size_t ws_size,
                              hipStream_t stream) {
    const float* X   = (const float*)d_in[0];
    const int*   ei  = (const int*)d_in[1];
    const float* W1  = (const float*)d_in[2];
    const float* as1 = (const float*)d_in[3];
    const float* ad1 = (const float*)d_in[4];
    const float* b1  = (const float*)d_in[5];
    const float* W2  = (const float*)d_in[6];
    const float* as2 = (const float*)d_in[7];
    const float* ad2 = (const float*)d_in[8];
    const float* b2  = (const float*)d_in[9];
    float* out = (float*)d_out;

    // workspace layout (~10 MB total)
    float* f = (float*)d_ws;
    float* p_src1 = f;                       f += NH1 * IN_FEAT;   // 1600
    float* p_dst1 = f;                       f += NH1 * IN_FEAT;   // 1600
    float* als1   = f;                       f += N_NODES * NH1;   // 80000
    float* ald1   = f;                       f += N_NODES * NH1;
    float* emax1  = f;                       f += N_NODES * NH1;
    float* den1   = f;                       f += N_NODES * NH1;
    float* als2   = f;                       f += N_NODES;
    float* ald2   = f;                       f += N_NODES;
    float* emax2  = f;                       f += N_NODES;
    float* den2   = f;                       f += N_NODES;
    float* h2     = f;                       f += (size_t)N_NODES * OUT_FEAT;  // 2M
    int* counts = (int*)f;
    int* cursor = counts + N_NODES;
    int* offs   = cursor + N_NODES;          // N_NODES+1
    int* esrc   = offs + N_NODES + 1;        // ET

    // zero/fill accumulators every call (harness does not re-poison)
    hipMemsetAsync(counts, 0, sizeof(int) * N_NODES * 2, stream);  // counts + cursor
    hipMemsetAsync(den1, 0, sizeof(float) * N_NODES * NH1, stream);
    hipMemsetAsync(den2, 0, sizeof(float) * N_NODES, stream);
    fill_f<<<(N_NODES * NH1 + 255) / 256, 256, 0, stream>>>(emax1, -INFINITY, N_NODES * NH1);
    fill_f<<<(N_NODES + 255) / 256, 256, 0, stream>>>(emax2, -INFINITY, N_NODES);

    // CSR build (shared by both layers)
    count_k<<<(ET + 255) / 256, 256, 0, stream>>>(ei, counts);
    scan_k<<<1, 1024, 0, stream>>>(counts, offs);
    scatter_k<<<(ET + 255) / 256, 256, 0, stream>>>(ei, offs, cursor, esrc);

    // ---- layer 1 (aggregate-first, fused) ----
    pvec_k<<<(2 * NH1 * IN_FEAT + 255) / 256, 256, 0, stream>>>(W1, as1, ad1, p_src1, p_dst1);
    att1x<<<N_NODES, 512, 0, stream>>>(X, p_src1, p_dst1, als1, ald1);
    edge_max_k<NH1><<<(ET * NH1 + 255) / 256, 256, 0, stream>>>(ei, als1, ald1, emax1);
    edge_den_k<NH1><<<(ET * NH1 + 255) / 256, 256, 0, stream>>>(ei, als1, ald1, emax1, den1);
    mega1<<<N_NODES / NT, 512, 0, stream>>>(X, W1, b1, als1, ald1, emax1, den1,
                                            offs, esrc, W2, h2);

    // ---- layer 2 (GEMM-first; h2 already computed by mega1) ----
    att2k<<<N_NODES, 64, 0, stream>>>(h2, as2, ad2, als2, ald2);
    edge_max_k<1><<<(ET + 255) / 256, 256, 0, stream>>>(ei, als2, ald2, emax2);
    edge_den_k<1><<<(ET + 255) / 256, 256, 0, stream>>>(ei, als2, ald2, emax2, den2);
    agg2_csr<<<N_NODES, 256, 0, stream>>>(h2, als2, ald2, emax2, den2, offs, esrc, b2, out);
}

// Round 3
// 775.751 us; speedup vs baseline: 2.5327x; 2.5327x over previous
//
#include <hip/hip_runtime.h>
#include <math.h>

#define N_NODES 10000
#define N_EDGES 80000
#define ET (N_EDGES + N_NODES)   // 90000 edges incl. self-loops
#define IN_FEAT 200
#define HID 400
#define NH1 8
#define F1 (NH1 * HID)           // 3200
#define OUT_FEAT 200
#define NEG_SLOPE 0.2f

#define M_PAD 10048              // 157 * 64
#define K1 224                   // per-head K pad (200 -> 224 = 7*32)
#define HSL (NH1 * K1)           // 1792 bf16 per node in xagg
#define XH_K 416                 // per-head hidden K pad (400 -> 416 = 13*32)
#define N2_PAD 224               // output-col pad (200 -> 224 = 14*16)

typedef __attribute__((ext_vector_type(8))) short short8_t;
typedef __attribute__((ext_vector_type(4))) float f32x4;

// ---------- helpers ----------

__device__ inline void edge_sd(const int* __restrict__ ei, int e, int& s, int& d) {
    if (e < N_EDGES) { s = ei[e]; d = ei[N_EDGES + e]; }
    else { s = e - N_EDGES; d = s; }
}

__device__ inline void atomicMaxF(float* addr, float val) {
    if (val >= 0.f) atomicMax((int*)addr, __float_as_int(val));
    else            atomicMin((unsigned int*)addr, (unsigned int)__float_as_uint(val));
}

__device__ inline unsigned short f2bf(float x) {
    unsigned u = __float_as_uint(x);
    unsigned r = u + 0x7FFFu + ((u >> 16) & 1u);
    return (unsigned short)(r >> 16);
}

// ---------- init: emax=-inf, den=0, counts/cursor=0 ----------
__global__ __launch_bounds__(256) void init_k(float* __restrict__ emax1, float* __restrict__ den1,
                                              float* __restrict__ emax2, float* __restrict__ den2,
                                              int* __restrict__ counts, int* __restrict__ cursor) {
    int i = blockIdx.x * blockDim.x + threadIdx.x;
    if (i < N_NODES * NH1) { emax1[i] = -INFINITY; den1[i] = 0.f; }
    if (i < N_NODES) { emax2[i] = -INFINITY; den2[i] = 0.f; counts[i] = 0; cursor[i] = 0; }
}

// ---------- weight prep: W1bt[h][c][k] bf16, k-contiguous, k padded to 224 ----------
__global__ __launch_bounds__(256) void prep_w1(const float* __restrict__ W1,
                                               unsigned short* __restrict__ W1bt) {
    int idx = blockIdx.x * blockDim.x + threadIdx.x;
    if (idx >= NH1 * HID * K1) return;
    int h = idx / (HID * K1);
    int rem = idx - h * (HID * K1);
    int c = rem / K1, k = rem - c * K1;
    float v = (k < IN_FEAT) ? W1[(size_t)k * F1 + h * HID + c] : 0.f;
    W1bt[idx] = f2bf(v);
}

// ---------- weight prep: W2bt[c][h][k1] bf16 (c<224, k1<416) ----------
__global__ __launch_bounds__(256) void prep_w2(const float* __restrict__ W2,
                                               unsigned short* __restrict__ W2bt) {
    int idx = blockIdx.x * blockDim.x + threadIdx.x;
    if (idx >= N2_PAD * NH1 * XH_K) return;
    int c = idx / (NH1 * XH_K);
    int rem = idx - c * (NH1 * XH_K);
    int h = rem / XH_K, k1 = rem - h * XH_K;
    float v = (c < OUT_FEAT && k1 < HID) ? W2[(size_t)(h * HID + k1) * OUT_FEAT + c] : 0.f;
    W2bt[idx] = f2bf(v);
}

// ---------- p-vectors: p_src1[h,k] = sum_c W1[k, h*400+c] * a_src1[h,c] ----------
__global__ __launch_bounds__(256) void pvec_k(const float* __restrict__ W1,
                                              const float* __restrict__ a_src,
                                              const float* __restrict__ a_dst,
                                              float* __restrict__ p_src,
                                              float* __restrict__ p_dst) {
    int idx = blockIdx.x * blockDim.x + threadIdx.x;
    if (idx >= 2 * NH1 * IN_FEAT) return;
    int which = idx / (NH1 * IN_FEAT);
    int r = idx - which * (NH1 * IN_FEAT);
    int h = r / IN_FEAT, k = r - h * IN_FEAT;
    const float* av = (which == 0 ? a_src : a_dst) + h * HID;
    const float* wrow = W1 + (size_t)k * F1 + h * HID;
    float acc = 0.f;
    for (int c = 0; c < HID; ++c) acc += wrow[c] * av[c];
    (which == 0 ? p_src : p_dst)[h * IN_FEAT + k] = acc;
}

// ---------- attention logits layer 1 ----------
__global__ __launch_bounds__(512) void att1x(const float* __restrict__ X,
                                             const float* __restrict__ p_src,
                                             const float* __restrict__ p_dst,
                                             float* __restrict__ als,
                                             float* __restrict__ ald) {
    const int n    = blockIdx.x;
    const int head = threadIdx.x >> 6;
    const int lane = threadIdx.x & 63;
    const float* xp = X + (size_t)n * IN_FEAT;
    const float* ps = p_src + head * IN_FEAT;
    const float* pd = p_dst + head * IN_FEAT;
    float ss = 0.f, sd = 0.f;
    for (int k = lane; k < IN_FEAT; k += 64) {
        float v = xp[k];
        ss += v * ps[k];
        sd += v * pd[k];
    }
    for (int off = 32; off; off >>= 1) {
        ss += __shfl_down(ss, off);
        sd += __shfl_down(sd, off);
    }
    if (lane == 0) { als[n * NH1 + head] = ss; ald[n * NH1 + head] = sd; }
}

// ---------- attention logits layer 2 ----------
__global__ __launch_bounds__(64) void att2k(const float* __restrict__ Hh,
                                            const float* __restrict__ a_src,
                                            const float* __restrict__ a_dst,
                                            float* __restrict__ als,
                                            float* __restrict__ ald) {
    const int n    = blockIdx.x;
    const int lane = threadIdx.x;
    const float* hp = Hh + (size_t)n * OUT_FEAT;
    float ss = 0.f, sd = 0.f;
    for (int c = lane; c < OUT_FEAT; c += 64) {
        float v = hp[c];
        ss += v * a_src[c];
        sd += v * a_dst[c];
    }
    for (int off = 32; off; off >>= 1) {
        ss += __shfl_down(ss, off);
        sd += __shfl_down(sd, off);
    }
    if (lane == 0) { als[n] = ss; ald[n] = sd; }
}

// ---------- CSR build ----------
__global__ __launch_bounds__(256) void count_k(const int* __restrict__ ei, int* __restrict__ counts) {
    int e = blockIdx.x * blockDim.x + threadIdx.x;
    if (e >= ET) return;
    int s, d; edge_sd(ei, e, s, d);
    atomicAdd(&counts[d], 1);
}

__global__ __launch_bounds__(1024) void scan_k(const int* __restrict__ counts, int* __restrict__ offs) {
    __shared__ int part[1024];
    const int tid = threadIdx.x;
    const int base = tid * 10;
    int loc[10];
    int s = 0;
    for (int i = 0; i < 10; ++i) {
        int idx = base + i;
        int c = (idx < N_NODES) ? counts[idx] : 0;
        loc[i] = s; s += c;
    }
    part[tid] = s;
    __syncthreads();
    for (int off = 1; off < 1024; off <<= 1) {
        int v = (tid >= off) ? part[tid - off] : 0;
        __syncthreads();
        part[tid] += v;
        __syncthreads();
    }
    int pre = (tid > 0) ? part[tid - 1] : 0;
    for (int i = 0; i < 10; ++i) {
        int idx = base + i;
        if (idx < N_NODES) offs[idx] = pre + loc[i];
    }
    if (tid == 1023) offs[N_NODES] = part[1023];
}

__global__ __launch_bounds__(256) void scatter_k(const int* __restrict__ ei,
                                                 const int* __restrict__ offs,
                                                 int* __restrict__ cursor,
                                                 int* __restrict__ esrc) {
    int e = blockIdx.x * blockDim.x + threadIdx.x;
    if (e >= ET) return;
    int s, d; edge_sd(ei, e, s, d);
    int pos = atomicAdd(&cursor[d], 1);
    esrc[offs[d] + pos] = s;
}

// ---------- edge softmax stats ----------
template <int H>
__global__ __launch_bounds__(256) void edge_max_k(const int* __restrict__ ei,
                                                  const float* __restrict__ als,
                                                  const float* __restrict__ ald,
                                                  float* __restrict__ emax) {
    int idx = blockIdx.x * blockDim.x + threadIdx.x;
    if (idx >= ET * H) return;
    int e = idx / H, h = idx - e * H;
    int s, d; edge_sd(ei, e, s, d);
    float v = als[s * H + h] + ald[d * H + h];
    v = v > 0.f ? v : NEG_SLOPE * v;
    atomicMaxF(&emax[d * H + h], v);
}

template <int H>
__global__ __launch_bounds__(256) void edge_den_k(const int* __restrict__ ei,
                                                  const float* __restrict__ als,
                                                  const float* __restrict__ ald,
                                                  const float* __restrict__ emax,
                                                  float* __restrict__ den) {
    int idx = blockIdx.x * blockDim.x + threadIdx.x;
    if (idx >= ET * H) return;
    int e = idx / H, h = idx - e * H;
    int s, d; edge_sd(ei, e, s, d);
    float v = als[s * H + h] + ald[d * H + h];
    v = v > 0.f ? v : NEG_SLOPE * v;
    unsafeAtomicAdd(&den[d * H + h], __expf(v - emax[d * H + h]));
}

// ---------- Stage A: xagg[n,h,0:224] (bf16) = sum_e alpha[e,h] * X[src_e,:] ----------
// 8 waves/block, one node per wave; accumulators in registers.
__global__ __launch_bounds__(512) void agg1x(const float* __restrict__ X,
                                             const float* __restrict__ als1,
                                             const float* __restrict__ ald1,
                                             const float* __restrict__ emax1,
                                             const float* __restrict__ den1,
                                             const int* __restrict__ offs,
                                             const int* __restrict__ esrc,
                                             unsigned short* __restrict__ xaggb) {
    __shared__ unsigned short sb[8][HSL];   // 28672 B
    const int wave = threadIdx.x >> 6;
    const int lane = threadIdx.x & 63;
    const int n = blockIdx.x * 8 + wave;    // < M_PAD always

    if (n < N_NODES) {
        float acc[NH1][4];
#pragma unroll
        for (int h = 0; h < NH1; ++h)
#pragma unroll
            for (int g = 0; g < 4; ++g) acc[h][g] = 0.f;

        float aldv = 0.f, em = 0.f, dn = 1.f;
        if (lane < NH1) {
            aldv = ald1[n * NH1 + lane];
            em   = emax1[n * NH1 + lane];
            dn   = den1[n * NH1 + lane];
        }
        const int beg = offs[n], end = offs[n + 1];
        for (int t = beg; t < end; ++t) {
            const int s = esrc[t];
            float aval = 0.f;
            if (lane < NH1) {
                float v = als1[s * NH1 + lane] + aldv;
                v = v > 0.f ? v : NEG_SLOPE * v;
                aval = __expf(v - em) / dn;
            }
            const float* xp = X + (size_t)s * IN_FEAT;
            float x0 = xp[lane];
            float x1 = xp[64 + lane];
            float x2 = xp[128 + lane];
            float x3 = (lane < 8) ? xp[192 + lane] : 0.f;
#pragma unroll
            for (int h = 0; h < NH1; ++h) {
                float a = __shfl(aval, h);
                acc[h][0] += a * x0;
                acc[h][1] += a * x1;
                acc[h][2] += a * x2;
                acc[h][3] += a * x3;
            }
        }
#pragma unroll
        for (int h = 0; h < NH1; ++h) {
            sb[wave][h * K1 + lane]        = f2bf(acc[h][0]);
            sb[wave][h * K1 + 64 + lane]   = f2bf(acc[h][1]);
            sb[wave][h * K1 + 128 + lane]  = f2bf(acc[h][2]);
            if (lane < 32) {
                unsigned short v3 = (lane < 8) ? f2bf(acc[h][3]) : (unsigned short)0;
                sb[wave][h * K1 + 192 + lane] = v3;  // cols 192..199 real, 200..223 zero pad
            }
        }
    } else {
        for (int j = lane; j < HSL; j += 64) sb[wave][j] = 0;
    }
    __syncthreads();
    // vectorized store: 8*1792 ushorts = 1792 16B chunks
    const uint4* s4 = (const uint4*)(&sb[0][0]);
    uint4* d4 = (uint4*)(xaggb + (size_t)blockIdx.x * 8 * HSL);
    for (int c = threadIdx.x; c < 8 * HSL / 8; c += 512) d4[c] = s4[c];
}

// ---------- GEMM1 (head h): xh = elu(xagg_h @ W1_h + b1_h), bf16 out ----------
// 4 waves; wave computes 16 rows x 400 cols (25 n-frags). grid = 157 m-tiles.
__global__ __launch_bounds__(256) void gemm1_h(const unsigned short* __restrict__ xaggb,
                                               const unsigned short* __restrict__ W1bt,
                                               const float* __restrict__ b1,
                                               unsigned short* __restrict__ xh,
                                               int h) {
    const int wave = threadIdx.x >> 6;
    const int lane = threadIdx.x & 63;
    const int row  = lane & 15;
    const int kg   = lane >> 4;
    const int m0   = blockIdx.x * 64 + wave * 16;

    const unsigned short* ap = xaggb + (size_t)(m0 + row) * HSL + h * K1 + kg * 8;
    const unsigned short* bp = W1bt + ((size_t)h * HID + row) * K1 + kg * 8;

    f32x4 acc[25];
#pragma unroll
    for (int j = 0; j < 25; ++j) acc[j] = (f32x4){0.f, 0.f, 0.f, 0.f};

    for (int ks = 0; ks < 7; ++ks) {
        short8_t a = *(const short8_t*)(ap + ks * 32);
#pragma unroll
        for (int j = 0; j < 25; ++j) {
            short8_t b = *(const short8_t*)(bp + (size_t)j * 16 * K1 + ks * 32);
            acc[j] = __builtin_amdgcn_mfma_f32_16x16x32_bf16(a, b, acc[j], 0, 0, 0);
        }
    }
#pragma unroll
    for (int j = 0; j < 25; ++j) {
        int cc = j * 16 + row;
        float bias = b1[h * HID + cc];
#pragma unroll
        for (int r = 0; r < 4; ++r) {
            int rr = m0 + kg * 4 + r;
            float v = acc[j][r] + bias;
            v = v > 0.f ? v : (__expf(v) - 1.f);
            xh[(size_t)rr * XH_K + cc] = (rr < N_NODES) ? f2bf(v) : (unsigned short)0;
        }
    }
}

// ---------- GEMM2 (head h): h2 += xh @ W2_h  (fp32 accumulate in global) ----------
// 4 waves: block tile 64 rows x 32 cols; wave = 32 rows x 16 cols (2 m-frags).
__global__ __launch_bounds__(256) void gemm2_h(const unsigned short* __restrict__ xh,
                                               const unsigned short* __restrict__ W2bt,
                                               float* __restrict__ h2,
                                               int h) {
    const int wave  = threadIdx.x >> 6;
    const int lane  = threadIdx.x & 63;
    const int row   = lane & 15;
    const int kg    = lane >> 4;
    const int mhalf = wave & 1;
    const int nq    = wave >> 1;
    const int m0    = blockIdx.x * 64 + mhalf * 32;
    const int n0    = blockIdx.y * 32 + nq * 16;

    const unsigned short* ap = xh + (size_t)(m0 + row) * XH_K + kg * 8;
    const unsigned short* bp = W2bt + ((size_t)(n0 + row) * NH1 + h) * XH_K + kg * 8;

    f32x4 acc0 = {0.f, 0.f, 0.f, 0.f}, acc1 = {0.f, 0.f, 0.f, 0.f};
    for (int ks = 0; ks < 13; ++ks) {
        short8_t a0 = *(const short8_t*)(ap + ks * 32);
        short8_t a1 = *(const short8_t*)(ap + (size_t)16 * XH_K + ks * 32);
        short8_t b  = *(const short8_t*)(bp + ks * 32);
        acc0 = __builtin_amdgcn_mfma_f32_16x16x32_bf16(a0, b, acc0, 0, 0, 0);
        acc1 = __builtin_amdgcn_mfma_f32_16x16x32_bf16(a1, b, acc1, 0, 0, 0);
    }
    const int cc = n0 + row;
    if (cc < OUT_FEAT) {
#pragma unroll
        for (int r = 0; r < 4; ++r) {
            int rr = m0 + kg * 4 + r;
            if (rr < N_NODES) h2[(size_t)rr * OUT_FEAT + cc] += acc0[r];
            rr += 16;
            if (rr < N_NODES) h2[(size_t)rr * OUT_FEAT + cc] += acc1[r];
        }
    }
}

// ---------- layer-2 aggregation ----------
__global__ __launch_bounds__(256) void agg2_csr(const float* __restrict__ h2,
                                                const float* __restrict__ als2,
                                                const float* __restrict__ ald2,
                                                const float* __restrict__ emax2,
                                                const float* __restrict__ den2,
                                                const int* __restrict__ offs,
                                                const int* __restrict__ esrc,
                                                const float* __restrict__ b2,
                                                float* __restrict__ out) {
    const int n = blockIdx.x;
    const int k = threadIdx.x;
    if (k >= OUT_FEAT) return;
    const float aldn = ald2[n], em = emax2[n], dn = den2[n];
    const int beg = offs[n], end = offs[n + 1];
    float acc = 0.f;
    for (int t = beg; t < end; ++t) {
        int s = esrc[t];
        float v = als2[s] + aldn;
        v = v > 0.f ? v : NEG_SLOPE * v;
        float a = __expf(v - em) / dn;
        acc += a * h2[(size_t)s * OUT_FEAT + k];
    }
    out[(size_t)n * OUT_FEAT + k] = acc + b2[k];
}

// ---------- launch ----------
extern "C" void kernel_launch(void* const* d_in, const int* in_sizes, int n_in,
                              void* d_out, int out_size, void* d_ws, size_t ws_size,
                              hipStream_t stream) {
    const float* X   = (const float*)d_in[0];
    const int*   ei  = (const int*)d_in[1];
    const float* W1  = (const float*)d_in[2];
    const float* as1 = (const float*)d_in[3];
    const float* ad1 = (const float*)d_in[4];
    const float* b1  = (const float*)d_in[5];
    const float* W2  = (const float*)d_in[6];
    const float* as2 = (const float*)d_in[7];
    const float* ad2 = (const float*)d_in[8];
    const float* b2  = (const float*)d_in[9];
    float* out = (float*)d_out;

    // workspace carve (256B-aligned chunks), total ~58 MB
    char* base = (char*)d_ws;
    auto carve = [&](size_t bytes) -> void* {
        void* p = (void*)base;
        base += (bytes + 255) & ~(size_t)255;
        return p;
    };
    float* p_src1 = (float*)carve(NH1 * IN_FEAT * 4);
    float* p_dst1 = (float*)carve(NH1 * IN_FEAT * 4);
    float* als1   = (float*)carve(N_NODES * NH1 * 4);
    float* ald1   = (float*)carve(N_NODES * NH1 * 4);
    float* emax1  = (float*)carve(N_NODES * NH1 * 4);
    float* den1   = (float*)carve(N_NODES * NH1 * 4);
    float* als2   = (float*)carve(N_NODES * 4);
    float* ald2   = (float*)carve(N_NODES * 4);
    float* emax2  = (float*)carve(N_NODES * 4);
    float* den2   = (float*)carve(N_NODES * 4);
    float* h2     = (float*)carve((size_t)N_NODES * OUT_FEAT * 4);
    int* counts   = (int*)carve(N_NODES * 4);
    int* cursor   = (int*)carve(N_NODES * 4);
    int* offs     = (int*)carve((N_NODES + 1) * 4);
    int* esrc     = (int*)carve(ET * 4);
    unsigned short* xaggb = (unsigned short*)carve((size_t)M_PAD * HSL * 2);
    unsigned short* xh    = (unsigned short*)carve((size_t)M_PAD * XH_K * 2);
    unsigned short* W1bt  = (unsigned short*)carve((size_t)NH1 * HID * K1 * 2);
    unsigned short* W2bt  = (unsigned short*)carve((size_t)N2_PAD * NH1 * XH_K * 2);

    // per-call init (harness does not re-poison between replays)
    init_k<<<(N_NODES * NH1 + 255) / 256, 256, 0, stream>>>(emax1, den1, emax2, den2, counts, cursor);
    hipMemsetAsync(h2, 0, (size_t)N_NODES * OUT_FEAT * 4, stream);
    hipMemsetAsync(xh, 0, (size_t)M_PAD * XH_K * 2, stream);

    // CSR + weight prep + logits
    count_k<<<(ET + 255) / 256, 256, 0, stream>>>(ei, counts);
    scan_k<<<1, 1024, 0, stream>>>(counts, offs);
    scatter_k<<<(ET + 255) / 256, 256, 0, stream>>>(ei, offs, cursor, esrc);
    prep_w1<<<(NH1 * HID * K1 + 255) / 256, 256, 0, stream>>>(W1, W1bt);
    prep_w2<<<(N2_PAD * NH1 * XH_K + 255) / 256, 256, 0, stream>>>(W2, W2bt);
    pvec_k<<<(2 * NH1 * IN_FEAT + 255) / 256, 256, 0, stream>>>(W1, as1, ad1, p_src1, p_dst1);
    att1x<<<N_NODES, 512, 0, stream>>>(X, p_src1, p_dst1, als1, ald1);
    edge_max_k<NH1><<<(ET * NH1 + 255) / 256, 256, 0, stream>>>(ei, als1, ald1, emax1);
    edge_den_k<NH1><<<(ET * NH1 + 255) / 256, 256, 0, stream>>>(ei, als1, ald1, emax1, den1);

    // Stage A: aggregated features (bf16, padded)
    agg1x<<<M_PAD / 8, 512, 0, stream>>>(X, als1, ald1, emax1, den1, offs, esrc, xaggb);

    // per-head MFMA GEMMs
    for (int h = 0; h < NH1; ++h) {
        gemm1_h<<<M_PAD / 64, 256, 0, stream>>>(xaggb, W1bt, b1, xh, h);
        gemm2_h<<<dim3(M_PAD / 64, N2_PAD / 32), 256, 0, stream>>>(xh, W2bt, h2, h);
    }

    // layer 2 softmax + aggregation (fp32)
    att2k<<<N_NODES, 64, 0, stream>>>(h2, as2, ad2, als2, ald2);
    edge_max_k<1><<<(ET + 255) / 256, 256, 0, stream>>>(ei, als2, ald2, emax2);
    edge_den_k<1><<<(ET + 255) / 256, 256, 0, stream>>>(ei, als2, ald2, emax2, den2);
    agg2_csr<<<N_NODES, 256, 0, stream>>>(h2, als2, ald2, emax2, den2, offs, esrc, b2, out);
}

// Round 4
// 459.017 us; speedup vs baseline: 4.2803x; 1.6900x over previous
//
#include <hip/hip_runtime.h>
#include <math.h>

#define N_NODES 10000
#define N_EDGES 80000
#define ET (N_EDGES + N_NODES)   // 90000 edges incl. self-loops
#define IN_FEAT 200
#define HID 400
#define NH1 8
#define F1 (NH1 * HID)           // 3200
#define OUT_FEAT 200
#define NEG_SLOPE 0.2f

#define M_PAD 10048              // 157 * 64
#define K1 224                   // per-head K pad (200 -> 224 = 7*32)
#define HSL (NH1 * K1)           // 1792 bf16 per node in xagg
#define XH_K 416                 // per-head hidden K pad (400 -> 416 = 13*32)
#define KALL (NH1 * XH_K)        // 3328 = fused K for gemm2
#define N2P2 256                 // W2bt row pad (cols of h2)

typedef __attribute__((ext_vector_type(8))) short short8_t;
typedef __attribute__((ext_vector_type(4))) float f32x4;

// ---------- helpers ----------

__device__ inline void edge_sd(const int* __restrict__ ei, int e, int& s, int& d) {
    if (e < N_EDGES) { s = ei[e]; d = ei[N_EDGES + e]; }
    else { s = e - N_EDGES; d = s; }
}

__device__ inline void atomicMaxF(float* addr, float val) {
    if (val >= 0.f) atomicMax((int*)addr, __float_as_int(val));
    else            atomicMin((unsigned int*)addr, (unsigned int)__float_as_uint(val));
}

__device__ inline unsigned short f2bf(float x) {
    unsigned u = __float_as_uint(x);
    unsigned r = u + 0x7FFFu + ((u >> 16) & 1u);
    return (unsigned short)(r >> 16);
}

// ---------- init ----------
__global__ __launch_bounds__(256) void init_k(float* __restrict__ emax1, float* __restrict__ den1,
                                              float* __restrict__ emax2, float* __restrict__ den2,
                                              int* __restrict__ counts, int* __restrict__ cursor) {
    int i = blockIdx.x * blockDim.x + threadIdx.x;
    if (i < N_NODES * NH1) { emax1[i] = -INFINITY; den1[i] = 0.f; }
    if (i < N_NODES) { emax2[i] = -INFINITY; den2[i] = 0.f; counts[i] = 0; cursor[i] = 0; }
}

// ---------- weight prep: W1bt[h][c][k] bf16, k padded to 224 ----------
__global__ __launch_bounds__(256) void prep_w1(const float* __restrict__ W1,
                                               unsigned short* __restrict__ W1bt) {
    int idx = blockIdx.x * blockDim.x + threadIdx.x;
    if (idx >= NH1 * HID * K1) return;
    int h = idx / (HID * K1);
    int rem = idx - h * (HID * K1);
    int c = rem / K1, k = rem - c * K1;
    float v = (k < IN_FEAT) ? W1[(size_t)k * F1 + h * HID + c] : 0.f;
    W1bt[idx] = f2bf(v);
}

// ---------- weight prep: W2bt[c][h*416+k1] bf16, c padded to 256 ----------
__global__ __launch_bounds__(256) void prep_w2(const float* __restrict__ W2,
                                               unsigned short* __restrict__ W2bt) {
    int idx = blockIdx.x * blockDim.x + threadIdx.x;
    if (idx >= N2P2 * KALL) return;
    int c = idx / KALL;
    int rem = idx - c * KALL;
    int h = rem / XH_K, k1 = rem - h * XH_K;
    float v = (c < OUT_FEAT && k1 < HID) ? W2[(size_t)(h * HID + k1) * OUT_FEAT + c] : 0.f;
    W2bt[idx] = f2bf(v);
}

// ---------- p-vectors ----------
__global__ __launch_bounds__(256) void pvec_k(const float* __restrict__ W1,
                                              const float* __restrict__ a_src,
                                              const float* __restrict__ a_dst,
                                              float* __restrict__ p_src,
                                              float* __restrict__ p_dst) {
    int idx = blockIdx.x * blockDim.x + threadIdx.x;
    if (idx >= 2 * NH1 * IN_FEAT) return;
    int which = idx / (NH1 * IN_FEAT);
    int r = idx - which * (NH1 * IN_FEAT);
    int h = r / IN_FEAT, k = r - h * IN_FEAT;
    const float* av = (which == 0 ? a_src : a_dst) + h * HID;
    const float* wrow = W1 + (size_t)k * F1 + h * HID;
    float acc = 0.f;
    for (int c = 0; c < HID; ++c) acc += wrow[c] * av[c];
    (which == 0 ? p_src : p_dst)[h * IN_FEAT + k] = acc;
}

// ---------- attention logits layer 1 ----------
__global__ __launch_bounds__(512) void att1x(const float* __restrict__ X,
                                             const float* __restrict__ p_src,
                                             const float* __restrict__ p_dst,
                                             float* __restrict__ als,
                                             float* __restrict__ ald) {
    const int n    = blockIdx.x;
    const int head = threadIdx.x >> 6;
    const int lane = threadIdx.x & 63;
    const float* xp = X + (size_t)n * IN_FEAT;
    const float* ps = p_src + head * IN_FEAT;
    const float* pd = p_dst + head * IN_FEAT;
    float ss = 0.f, sd = 0.f;
    for (int k = lane; k < IN_FEAT; k += 64) {
        float v = xp[k];
        ss += v * ps[k];
        sd += v * pd[k];
    }
    for (int off = 32; off; off >>= 1) {
        ss += __shfl_down(ss, off);
        sd += __shfl_down(sd, off);
    }
    if (lane == 0) { als[n * NH1 + head] = ss; ald[n * NH1 + head] = sd; }
}

// ---------- attention logits layer 2 ----------
__global__ __launch_bounds__(64) void att2k(const float* __restrict__ Hh,
                                            const float* __restrict__ a_src,
                                            const float* __restrict__ a_dst,
                                            float* __restrict__ als,
                                            float* __restrict__ ald) {
    const int n    = blockIdx.x;
    const int lane = threadIdx.x;
    const float* hp = Hh + (size_t)n * OUT_FEAT;
    float ss = 0.f, sd = 0.f;
    for (int c = lane; c < OUT_FEAT; c += 64) {
        float v = hp[c];
        ss += v * a_src[c];
        sd += v * a_dst[c];
    }
    for (int off = 32; off; off >>= 1) {
        ss += __shfl_down(ss, off);
        sd += __shfl_down(sd, off);
    }
    if (lane == 0) { als[n] = ss; ald[n] = sd; }
}

// ---------- CSR build ----------
__global__ __launch_bounds__(256) void count_k(const int* __restrict__ ei, int* __restrict__ counts) {
    int e = blockIdx.x * blockDim.x + threadIdx.x;
    if (e >= ET) return;
    int s, d; edge_sd(ei, e, s, d);
    atomicAdd(&counts[d], 1);
}

__global__ __launch_bounds__(1024) void scan_k(const int* __restrict__ counts, int* __restrict__ offs) {
    __shared__ int part[1024];
    const int tid = threadIdx.x;
    const int base = tid * 10;
    int loc[10];
    int s = 0;
    for (int i = 0; i < 10; ++i) {
        int idx = base + i;
        int c = (idx < N_NODES) ? counts[idx] : 0;
        loc[i] = s; s += c;
    }
    part[tid] = s;
    __syncthreads();
    for (int off = 1; off < 1024; off <<= 1) {
        int v = (tid >= off) ? part[tid - off] : 0;
        __syncthreads();
        part[tid] += v;
        __syncthreads();
    }
    int pre = (tid > 0) ? part[tid - 1] : 0;
    for (int i = 0; i < 10; ++i) {
        int idx = base + i;
        if (idx < N_NODES) offs[idx] = pre + loc[i];
    }
    if (tid == 1023) offs[N_NODES] = part[1023];
}

__global__ __launch_bounds__(256) void scatter_k(const int* __restrict__ ei,
                                                 const int* __restrict__ offs,
                                                 int* __restrict__ cursor,
                                                 int* __restrict__ esrc) {
    int e = blockIdx.x * blockDim.x + threadIdx.x;
    if (e >= ET) return;
    int s, d; edge_sd(ei, e, s, d);
    int pos = atomicAdd(&cursor[d], 1);
    esrc[offs[d] + pos] = s;
}

// ---------- edge softmax stats ----------
template <int H>
__global__ __launch_bounds__(256) void edge_max_k(const int* __restrict__ ei,
                                                  const float* __restrict__ als,
                                                  const float* __restrict__ ald,
                                                  float* __restrict__ emax) {
    int idx = blockIdx.x * blockDim.x + threadIdx.x;
    if (idx >= ET * H) return;
    int e = idx / H, h = idx - e * H;
    int s, d; edge_sd(ei, e, s, d);
    float v = als[s * H + h] + ald[d * H + h];
    v = v > 0.f ? v : NEG_SLOPE * v;
    atomicMaxF(&emax[d * H + h], v);
}

template <int H>
__global__ __launch_bounds__(256) void edge_den_k(const int* __restrict__ ei,
                                                  const float* __restrict__ als,
                                                  const float* __restrict__ ald,
                                                  const float* __restrict__ emax,
                                                  float* __restrict__ den) {
    int idx = blockIdx.x * blockDim.x + threadIdx.x;
    if (idx >= ET * H) return;
    int e = idx / H, h = idx - e * H;
    int s, d; edge_sd(ei, e, s, d);
    float v = als[s * H + h] + ald[d * H + h];
    v = v > 0.f ? v : NEG_SLOPE * v;
    unsafeAtomicAdd(&den[d * H + h], __expf(v - emax[d * H + h]));
}

// ---------- Stage A: xagg[n,h,0:224] (bf16) ----------
__global__ __launch_bounds__(512) void agg1x(const float* __restrict__ X,
                                             const float* __restrict__ als1,
                                             const float* __restrict__ ald1,
                                             const float* __restrict__ emax1,
                                             const float* __restrict__ den1,
                                             const int* __restrict__ offs,
                                             const int* __restrict__ esrc,
                                             unsigned short* __restrict__ xaggb) {
    __shared__ unsigned short sb[8][HSL];   // 28672 B
    const int wave = threadIdx.x >> 6;
    const int lane = threadIdx.x & 63;
    const int n = blockIdx.x * 8 + wave;

    if (n < N_NODES) {
        float acc[NH1][4];
#pragma unroll
        for (int h = 0; h < NH1; ++h)
#pragma unroll
            for (int g = 0; g < 4; ++g) acc[h][g] = 0.f;

        float aldv = 0.f, em = 0.f, dn = 1.f;
        if (lane < NH1) {
            aldv = ald1[n * NH1 + lane];
            em   = emax1[n * NH1 + lane];
            dn   = den1[n * NH1 + lane];
        }
        const int beg = offs[n], end = offs[n + 1];
        for (int t = beg; t < end; ++t) {
            const int s = esrc[t];
            float aval = 0.f;
            if (lane < NH1) {
                float v = als1[s * NH1 + lane] + aldv;
                v = v > 0.f ? v : NEG_SLOPE * v;
                aval = __expf(v - em) / dn;
            }
            const float* xp = X + (size_t)s * IN_FEAT;
            float x0 = xp[lane];
            float x1 = xp[64 + lane];
            float x2 = xp[128 + lane];
            float x3 = (lane < 8) ? xp[192 + lane] : 0.f;
#pragma unroll
            for (int h = 0; h < NH1; ++h) {
                float a = __shfl(aval, h);
                acc[h][0] += a * x0;
                acc[h][1] += a * x1;
                acc[h][2] += a * x2;
                acc[h][3] += a * x3;
            }
        }
#pragma unroll
        for (int h = 0; h < NH1; ++h) {
            sb[wave][h * K1 + lane]        = f2bf(acc[h][0]);
            sb[wave][h * K1 + 64 + lane]   = f2bf(acc[h][1]);
            sb[wave][h * K1 + 128 + lane]  = f2bf(acc[h][2]);
            if (lane < 32) {
                unsigned short v3 = (lane < 8) ? f2bf(acc[h][3]) : (unsigned short)0;
                sb[wave][h * K1 + 192 + lane] = v3;
            }
        }
    } else {
        for (int j = lane; j < HSL; j += 64) sb[wave][j] = 0;
    }
    __syncthreads();
    const uint4* s4 = (const uint4*)(&sb[0][0]);
    uint4* d4 = (uint4*)(xaggb + (size_t)blockIdx.x * 8 * HSL);
    for (int c = threadIdx.x; c < 8 * HSL / 8; c += 512) d4[c] = s4[c];
}

// ---------- GEMM1: xh[:, col_off + 0:400] = elu(xagg_h @ W1_h + b1_h) ----------
// grid (157, nheads). h = h_base + blockIdx.y; xs = xh row stride (elements).
__global__ __launch_bounds__(256) void gemm1_all(const unsigned short* __restrict__ xaggb,
                                                 const unsigned short* __restrict__ W1bt,
                                                 const float* __restrict__ b1,
                                                 unsigned short* __restrict__ xh,
                                                 int h_base, int xs) {
    const int wave = threadIdx.x >> 6;
    const int lane = threadIdx.x & 63;
    const int row  = lane & 15;
    const int kg   = lane >> 4;
    const int h    = h_base + blockIdx.y;
    const int m0   = blockIdx.x * 64 + wave * 16;
    const int col_off = blockIdx.y * XH_K;

    const unsigned short* ap = xaggb + (size_t)(m0 + row) * HSL + h * K1 + kg * 8;
    const unsigned short* bp = W1bt + ((size_t)h * HID + row) * K1 + kg * 8;

    f32x4 acc[25];
#pragma unroll
    for (int j = 0; j < 25; ++j) acc[j] = (f32x4){0.f, 0.f, 0.f, 0.f};

    for (int ks = 0; ks < 7; ++ks) {
        short8_t a = *(const short8_t*)(ap + ks * 32);
#pragma unroll
        for (int j = 0; j < 25; ++j) {
            short8_t b = *(const short8_t*)(bp + (size_t)j * 16 * K1 + ks * 32);
            acc[j] = __builtin_amdgcn_mfma_f32_16x16x32_bf16(a, b, acc[j], 0, 0, 0);
        }
    }
#pragma unroll
    for (int j = 0; j < 25; ++j) {
        int cc = j * 16 + row;
        float bias = b1[h * HID + cc];
#pragma unroll
        for (int r = 0; r < 4; ++r) {
            int rr = m0 + kg * 4 + r;
            float v = acc[j][r] + bias;
            v = v > 0.f ? v : (__expf(v) - 1.f);
            xh[(size_t)rr * xs + col_off + cc] = (rr < N_NODES) ? f2bf(v) : (unsigned short)0;
        }
    }
}

// ---------- GEMM2 (parallel path): h2 = xh_all @ W2bt^T, K = 3328 ----------
// grid (157, 4): block tile 64x64; wave = 32x32 (2x2 frags).
__global__ __launch_bounds__(256) void gemm2_par(const unsigned short* __restrict__ xh,
                                                 const unsigned short* __restrict__ W2bt,
                                                 float* __restrict__ h2) {
    const int wave = threadIdx.x >> 6;
    const int lane = threadIdx.x & 63;
    const int row  = lane & 15;
    const int kg   = lane >> 4;
    const int m0   = blockIdx.x * 64 + (wave & 1) * 32;
    const int c0   = blockIdx.y * 64 + (wave >> 1) * 32;

    const unsigned short* ap0 = xh + (size_t)(m0 + row) * KALL + kg * 8;
    const unsigned short* ap1 = ap0 + (size_t)16 * KALL;
    const unsigned short* bp0 = W2bt + (size_t)(c0 + row) * KALL + kg * 8;
    const unsigned short* bp1 = bp0 + (size_t)16 * KALL;

    f32x4 a00 = {0.f,0.f,0.f,0.f}, a01 = {0.f,0.f,0.f,0.f};
    f32x4 a10 = {0.f,0.f,0.f,0.f}, a11 = {0.f,0.f,0.f,0.f};
    for (int ks = 0; ks < KALL / 32; ++ks) {
        short8_t a0 = *(const short8_t*)(ap0 + ks * 32);
        short8_t a1 = *(const short8_t*)(ap1 + ks * 32);
        short8_t b0 = *(const short8_t*)(bp0 + ks * 32);
        short8_t b1 = *(const short8_t*)(bp1 + ks * 32);
        a00 = __builtin_amdgcn_mfma_f32_16x16x32_bf16(a0, b0, a00, 0, 0, 0);
        a01 = __builtin_amdgcn_mfma_f32_16x16x32_bf16(a0, b1, a01, 0, 0, 0);
        a10 = __builtin_amdgcn_mfma_f32_16x16x32_bf16(a1, b0, a10, 0, 0, 0);
        a11 = __builtin_amdgcn_mfma_f32_16x16x32_bf16(a1, b1, a11, 0, 0, 0);
    }
    const int cc0 = c0 + row, cc1 = c0 + 16 + row;
#pragma unroll
    for (int r = 0; r < 4; ++r) {
        int rr0 = m0 + kg * 4 + r;
        int rr1 = rr0 + 16;
        if (rr0 < N_NODES) {
            if (cc0 < OUT_FEAT) h2[(size_t)rr0 * OUT_FEAT + cc0] = a00[r];
            if (cc1 < OUT_FEAT) h2[(size_t)rr0 * OUT_FEAT + cc1] = a01[r];
        }
        if (rr1 < N_NODES) {
            if (cc0 < OUT_FEAT) h2[(size_t)rr1 * OUT_FEAT + cc0] = a10[r];
            if (cc1 < OUT_FEAT) h2[(size_t)rr1 * OUT_FEAT + cc1] = a11[r];
        }
    }
}

// ---------- GEMM2 (serial fallback): h2 += xh_h @ W2_h ----------
__global__ __launch_bounds__(256) void gemm2_ser(const unsigned short* __restrict__ xh,
                                                 const unsigned short* __restrict__ W2bt,
                                                 float* __restrict__ h2, int h) {
    const int wave  = threadIdx.x >> 6;
    const int lane  = threadIdx.x & 63;
    const int row   = lane & 15;
    const int kg    = lane >> 4;
    const int m0    = blockIdx.x * 64 + (wave & 1) * 32;
    const int n0    = blockIdx.y * 32 + (wave >> 1) * 16;

    const unsigned short* ap = xh + (size_t)(m0 + row) * XH_K + kg * 8;
    const unsigned short* bp = W2bt + (size_t)(n0 + row) * KALL + h * XH_K + kg * 8;

    f32x4 acc0 = {0.f,0.f,0.f,0.f}, acc1 = {0.f,0.f,0.f,0.f};
    for (int ks = 0; ks < 13; ++ks) {
        short8_t a0 = *(const short8_t*)(ap + ks * 32);
        short8_t a1 = *(const short8_t*)(ap + (size_t)16 * XH_K + ks * 32);
        short8_t b  = *(const short8_t*)(bp + ks * 32);
        acc0 = __builtin_amdgcn_mfma_f32_16x16x32_bf16(a0, b, acc0, 0, 0, 0);
        acc1 = __builtin_amdgcn_mfma_f32_16x16x32_bf16(a1, b, acc1, 0, 0, 0);
    }
    const int cc = n0 + row;
    if (cc < OUT_FEAT) {
#pragma unroll
        for (int r = 0; r < 4; ++r) {
            int rr = m0 + kg * 4 + r;
            if (rr < N_NODES) h2[(size_t)rr * OUT_FEAT + cc] += acc0[r];
            rr += 16;
            if (rr < N_NODES) h2[(size_t)rr * OUT_FEAT + cc] += acc1[r];
        }
    }
}

// ---------- layer-2 aggregation ----------
__global__ __launch_bounds__(256) void agg2_csr(const float* __restrict__ h2,
                                                const float* __restrict__ als2,
                                                const float* __restrict__ ald2,
                                                const float* __restrict__ emax2,
                                                const float* __restrict__ den2,
                                                const int* __restrict__ offs,
                                                const int* __restrict__ esrc,
                                                const float* __restrict__ b2,
                                                float* __restrict__ out) {
    const int n = blockIdx.x;
    const int k = threadIdx.x;
    if (k >= OUT_FEAT) return;
    const float aldn = ald2[n], em = emax2[n], dn = den2[n];
    const int beg = offs[n], end = offs[n + 1];
    float acc = 0.f;
    for (int t = beg; t < end; ++t) {
        int s = esrc[t];
        float v = als2[s] + aldn;
        v = v > 0.f ? v : NEG_SLOPE * v;
        float a = __expf(v - em) / dn;
        acc += a * h2[(size_t)s * OUT_FEAT + k];
    }
    out[(size_t)n * OUT_FEAT + k] = acc + b2[k];
}

// ---------- launch ----------
extern "C" void kernel_launch(void* const* d_in, const int* in_sizes, int n_in,
                              void* d_out, int out_size, void* d_ws, size_t ws_size,
                              hipStream_t stream) {
    const float* X   = (const float*)d_in[0];
    const int*   ei  = (const int*)d_in[1];
    const float* W1  = (const float*)d_in[2];
    const float* as1 = (const float*)d_in[3];
    const float* ad1 = (const float*)d_in[4];
    const float* b1  = (const float*)d_in[5];
    const float* W2  = (const float*)d_in[6];
    const float* as2 = (const float*)d_in[7];
    const float* ad2 = (const float*)d_in[8];
    const float* b2  = (const float*)d_in[9];
    float* out = (float*)d_out;

    char* base = (char*)d_ws;
    auto carve = [&](size_t bytes) -> void* {
        void* p = (void*)base;
        base += (bytes + 255) & ~(size_t)255;
        return p;
    };
    float* p_src1 = (float*)carve(NH1 * IN_FEAT * 4);
    float* p_dst1 = (float*)carve(NH1 * IN_FEAT * 4);
    float* als1   = (float*)carve(N_NODES * NH1 * 4);
    float* ald1   = (float*)carve(N_NODES * NH1 * 4);
    float* emax1  = (float*)carve(N_NODES * NH1 * 4);
    float* den1   = (float*)carve(N_NODES * NH1 * 4);
    float* als2   = (float*)carve(N_NODES * 4);
    float* ald2   = (float*)carve(N_NODES * 4);
    float* emax2  = (float*)carve(N_NODES * 4);
    float* den2   = (float*)carve(N_NODES * 4);
    float* h2     = (float*)carve((size_t)N_NODES * OUT_FEAT * 4);
    int* counts   = (int*)carve(N_NODES * 4);
    int* cursor   = (int*)carve(N_NODES * 4);
    int* offs     = (int*)carve((N_NODES + 1) * 4);
    int* esrc     = (int*)carve(ET * 4);
    unsigned short* xaggb = (unsigned short*)carve((size_t)M_PAD * HSL * 2);
    unsigned short* W1bt  = (unsigned short*)carve((size_t)NH1 * HID * K1 * 2);
    unsigned short* W2bt  = (unsigned short*)carve((size_t)N2P2 * KALL * 2);

    // decide path by remaining workspace
    size_t used = (size_t)(base - (char*)d_ws);
    size_t xh_par_bytes = (size_t)M_PAD * KALL * 2;   // ~66.9 MB
    size_t xh_ser_bytes = (size_t)M_PAD * XH_K * 2;   // ~8.4 MB
    bool par = (ws_size > used) && ((ws_size - used) >= xh_par_bytes);
    unsigned short* xh = (unsigned short*)carve(par ? xh_par_bytes : xh_ser_bytes);

    // per-call init (harness does not re-poison between replays)
    init_k<<<(N_NODES * NH1 + 255) / 256, 256, 0, stream>>>(emax1, den1, emax2, den2, counts, cursor);

    // CSR + weight prep + logits
    count_k<<<(ET + 255) / 256, 256, 0, stream>>>(ei, counts);
    scan_k<<<1, 1024, 0, stream>>>(counts, offs);
    scatter_k<<<(ET + 255) / 256, 256, 0, stream>>>(ei, offs, cursor, esrc);
    prep_w1<<<(NH1 * HID * K1 + 255) / 256, 256, 0, stream>>>(W1, W1bt);
    prep_w2<<<(N2P2 * KALL + 255) / 256, 256, 0, stream>>>(W2, W2bt);
    pvec_k<<<(2 * NH1 * IN_FEAT + 255) / 256, 256, 0, stream>>>(W1, as1, ad1, p_src1, p_dst1);
    att1x<<<N_NODES, 512, 0, stream>>>(X, p_src1, p_dst1, als1, ald1);
    edge_max_k<NH1><<<(ET * NH1 + 255) / 256, 256, 0, stream>>>(ei, als1, ald1, emax1);
    edge_den_k<NH1><<<(ET * NH1 + 255) / 256, 256, 0, stream>>>(ei, als1, ald1, emax1, den1);

    // Stage A: aggregated features (bf16, padded)
    agg1x<<<M_PAD / 8, 512, 0, stream>>>(X, als1, ald1, emax1, den1, offs, esrc, xaggb);

    if (par) {
        // all heads in one dispatch; gemm2 as a single K=3328 GEMM
        gemm1_all<<<dim3(M_PAD / 64, NH1), 256, 0, stream>>>(xaggb, W1bt, b1, xh, 0, KALL);
        gemm2_par<<<dim3(M_PAD / 64, N2P2 / 64), 256, 0, stream>>>(xh, W2bt, h2);
    } else {
        hipMemsetAsync(h2, 0, (size_t)N_NODES * OUT_FEAT * 4, stream);
        for (int h = 0; h < NH1; ++h) {
            gemm1_all<<<dim3(M_PAD / 64, 1), 256, 0, stream>>>(xaggb, W1bt, b1, xh, h, XH_K);
            gemm2_ser<<<dim3(M_PAD / 64, 7), 256, 0, stream>>>(xh, W2bt, h2, h);
        }
    }

    // layer 2 softmax + aggregation (fp32)
    att2k<<<N_NODES, 64, 0, stream>>>(h2, as2, ad2, als2, ald2);
    edge_max_k<1><<<(ET + 255) / 256, 256, 0, stream>>>(ei, als2, ald2, emax2);
    edge_den_k<1><<<(ET + 255) / 256, 256, 0, stream>>>(ei, als2, ald2, emax2, den2);
    agg2_csr<<<N_NODES, 256, 0, stream>>>(h2, als2, ald2, emax2, den2, offs, esrc, b2, out);
}